// Round 6
// baseline (16451.059 us; speedup 1.0000x reference)
//
#include <hip/hip_runtime.h>
#include <stdint.h>

typedef __attribute__((ext_vector_type(4))) float float4v;
typedef __attribute__((ext_vector_type(8))) short short8v;   // 8 x bf16 (4 VGPRs)

static __device__ __forceinline__ float sigp(float x){ return 1.f/(1.f+expf(-x)); }

// fp32 -> bf16 (RNE) and back
static __device__ __forceinline__ unsigned short f2bf(float x){
  unsigned u = __float_as_uint(x);
  u += 0x7FFFu + ((u>>16)&1u);
  return (unsigned short)(u>>16);
}
static __device__ __forceinline__ float bf2f(unsigned short h){
  return __uint_as_float(((unsigned)h)<<16);
}

__global__ void sentf_k(float* __restrict__ o, int n, float v){
  int i = blockIdx.x*256 + threadIdx.x; if (i < n) o[i] = v;
}

// ---------------- prep: plink + histogram over (seq, link) ----------------
__global__ void prep_k(const int* __restrict__ links, const int* __restrict__ paths,
                       const int* __restrict__ seqs, int* __restrict__ plink,
                       int* __restrict__ cnt){
  int e = blockIdx.x*256 + threadIdx.x;
  if (e < 120000){
    int p = paths[e], s = seqs[e], l = links[e];
    plink[p*6 + s] = l;
    atomicAdd(&cnt[s*2000 + l], 1);
  }
}
__global__ void scan_k(const int* __restrict__ cnt, int* __restrict__ off, int* __restrict__ cur){
  __shared__ int part[256]; __shared__ int pref[256];
  int t = threadIdx.x;
  int lo = t*47, hi = lo+47; if (hi > 12000) hi = 12000;
  int s = 0;
  for (int i=lo;i<hi;i++) s += cnt[i];
  part[t] = s; __syncthreads();
  if (t==0){ int r=0; for (int i=0;i<256;i++){ pref[i]=r; r+=part[i]; } }
  __syncthreads();
  int r = pref[t];
  for (int i=lo;i<hi;i++){ off[i]=r; cur[i]=r; r+=cnt[i]; }
}
__global__ void fill2_k(const int* __restrict__ links, const int* __restrict__ paths,
                        const int* __restrict__ seqs, int* __restrict__ cur,
                        int* __restrict__ plist){
  int e = blockIdx.x*256 + threadIdx.x;
  if (e < 120000){
    int p = paths[e], s = seqs[e], l = links[e];
    int pos = atomicAdd(&cur[s*2000 + l], 1);
    plist[pos] = p;
  }
}

// ---------------- weight split: W -> (hi, lo) bf16 ----------------
__global__ void wcvt_k(const float* __restrict__ W, unsigned short* __restrict__ hi,
                       unsigned short* __restrict__ lo, int n){
  int i = blockIdx.x*256 + threadIdx.x;
  if (i < n){
    float x = W[i];
    unsigned short h = f2bf(x);
    hi[i] = h;
    lo[i] = f2bf(x - bf2f(h));
  }
}

// ---------------- state init: hi/lo pairs into both ping-pong buffers ----------------
__global__ void initp_k(const float* __restrict__ x0,
                        unsigned short* __restrict__ h0, unsigned short* __restrict__ l0,
                        unsigned short* __restrict__ h1, unsigned short* __restrict__ l1,
                        int Mreal){
  int i = blockIdx.x*256 + threadIdx.x;   // grid covers Mp*512
  int m = i >> 9, c = i & 511;
  float v = (c==0 && m < Mreal) ? x0[m] : 0.f;
  unsigned short hh = f2bf(v);
  unsigned short ll = f2bf(v - bf2f(hh));
  h0[i]=hh; l0[i]=ll; h1[i]=hh; l1[i]=ll;
}

// ---------------- MFMA split-bf16 GEMM, optionally fused GRU step -----------------
// C[M,1536] = A[M,512] @ W[1536,512]^T  via  Ahi@Whi + Alo@Whi + Ahi@Wlo
// ALL-REGISTER version: no LDS, no barriers. Each lane's MFMA fragment (8 bf16)
// is 16 contiguous bytes in global memory -> global_load_dwordx4 directly into
// operand registers. W is L2-resident (3 MB/XCD); A-slice shared by the 8
// consecutive cb-siblings (XCD-aware mapping: XCD = bid%8).
// Block = 128 threads = 2 waves (wn = col half), wave tile 32x96: mf=2, nf=6
// (nf spans all 3 gates: g=nf>>1, pp=nf&1 -> gate triple stays in-lane).
// __launch_bounds__(128,3): 3 waves/SIMD target (~170 VGPR cap).
__global__ __launch_bounds__(128,3) void gmfma_k(
    const unsigned short* __restrict__ Ahi, const unsigned short* __restrict__ Alo,
    const unsigned short* __restrict__ Whi, const unsigned short* __restrict__ Wlo,
    const float* __restrict__ bias, const float* __restrict__ GI,
    const int* __restrict__ plink, int s,
    float* __restrict__ OutF,
    unsigned short* __restrict__ Ohi, unsigned short* __restrict__ Olo,
    int M, int gru, int writeF)
{
  const int tid  = threadIdx.x;
  const int lane = tid & 63, wn = tid >> 6;
  const int bid = blockIdx.x;
  const int X = bid & 7, kk2 = bid >> 3;
  const int m0 = ((kk2 >> 3)*8 + X) * 32;   // 32-row m-block; cb fastest per XCD
  const int cb = kk2 & 7;
  const int c16 = lane & 15, kq = lane >> 4;

  // byte voffsets; rows are fixed per lane, k advances by 64 B per chunk
  int voA[2], voB[6];
#pragma unroll
  for (int mf = 0; mf < 2; ++mf)
    voA[mf] = (m0 + mf*16 + c16)*1024 + kq*16;
#pragma unroll
  for (int nf = 0; nf < 6; ++nf)
    voB[nf] = ((nf>>1)*512 + cb*64 + wn*32 + (nf&1)*16 + c16)*1024 + kq*16;

  const char* pAh = (const char*)Ahi;
  const char* pAl = (const char*)Alo;
  const char* pWh = (const char*)Whi;
  const char* pWl = (const char*)Wlo;

  float4v acc[2][6];
#pragma unroll
  for (int i = 0; i < 2; ++i)
#pragma unroll
    for (int j = 0; j < 6; ++j) acc[i][j] = (float4v){0.f,0.f,0.f,0.f};

  for (int kb = 0; kb < 16; ++kb){
    const int ko = kb*64;                   // 32 k-elems * 2 B
    short8v ah[2], bh[6], al[2], bl[6];
    // load order matches product-pass order -> compiler's per-use waitcnts
    // give a 3-stage pipeline within the iteration; no barriers anywhere.
#pragma unroll
    for (int mf = 0; mf < 2; ++mf) ah[mf] = *(const short8v*)(pAh + (voA[mf] + ko));
#pragma unroll
    for (int nf = 0; nf < 6; ++nf) bh[nf] = *(const short8v*)(pWh + (voB[nf] + ko));
#pragma unroll
    for (int mf = 0; mf < 2; ++mf) al[mf] = *(const short8v*)(pAl + (voA[mf] + ko));
#pragma unroll
    for (int nf = 0; nf < 6; ++nf) bl[nf] = *(const short8v*)(pWl + (voB[nf] + ko));
#pragma unroll
    for (int mf = 0; mf < 2; ++mf)
#pragma unroll
      for (int nf = 0; nf < 6; ++nf)
        acc[mf][nf] = __builtin_amdgcn_mfma_f32_16x16x32_bf16(ah[mf], bh[nf], acc[mf][nf], 0, 0, 0);
#pragma unroll
    for (int mf = 0; mf < 2; ++mf)
#pragma unroll
      for (int nf = 0; nf < 6; ++nf)
        acc[mf][nf] = __builtin_amdgcn_mfma_f32_16x16x32_bf16(al[mf], bh[nf], acc[mf][nf], 0, 0, 0);
#pragma unroll
    for (int mf = 0; mf < 2; ++mf)
#pragma unroll
      for (int nf = 0; nf < 6; ++nf)
        acc[mf][nf] = __builtin_amdgcn_mfma_f32_16x16x32_bf16(ah[mf], bl[nf], acc[mf][nf], 0, 0, 0);
  }

  // epilogue. C/D frag: col = lane&15, row = (lane>>4)*4 + reg.
  if (!gru){
#pragma unroll
    for (int pp = 0; pp < 2; ++pp){
      const int col = cb*64 + wn*32 + pp*16 + c16;
      const float b0f = bias[col], b1f = bias[512+col], b2f = bias[1024+col];
#pragma unroll
      for (int mf = 0; mf < 2; ++mf){
        const int mb = m0 + mf*16 + kq*4;
#pragma unroll
        for (int r = 0; r < 4; ++r){
          const int m = mb + r;
          if (m < M){
            float* c = OutF + (size_t)m*1536 + col;
            c[0]    = acc[mf][0+pp][r] + b0f;
            c[512]  = acc[mf][2+pp][r] + b1f;
            c[1024] = acc[mf][4+pp][r] + b2f;
          }
        }
      }
    }
  } else {
#pragma unroll
    for (int pp = 0; pp < 2; ++pp){
      const int col = cb*64 + wn*32 + pp*16 + c16;
      const float br = bias[col], bz = bias[512+col], bn = bias[1024+col];
#pragma unroll
      for (int mf = 0; mf < 2; ++mf){
        const int mb = m0 + mf*16 + kq*4;
#pragma unroll
        for (int r = 0; r < 4; ++r){
          const int m = mb + r;
          if (m < M){
            const int gr = plink ? plink[m*6 + s] : m;
            const float* gi = GI + (size_t)gr*1536 + col;
            const size_t ix = (size_t)m*512 + col;
            float hold = bf2f(Ahi[ix]) + bf2f(Alo[ix]);
            float rr = sigp(gi[0]    + acc[mf][0+pp][r] + br);
            float zz = sigp(gi[512]  + acc[mf][2+pp][r] + bz);
            float nn = 2.f*sigp(2.f*(gi[1024] + rr*(acc[mf][4+pp][r] + bn))) - 1.f; // tanh
            float h  = (1.f - zz)*nn + zz*hold;
            unsigned short hh = f2bf(h);
            Ohi[ix] = hh;
            Olo[ix] = f2bf(h - bf2f(hh));
            if (writeF) OutF[ix] = h;
          }
        }
      }
    }
  }
}

// ---------------- per-step segment-sum over hi/lo state; emits hi/lo agg at s==5 ----------------
__global__ void aggv_k(const unsigned short* __restrict__ Hh, const unsigned short* __restrict__ Hl,
                       const int* __restrict__ plist,
                       const int* __restrict__ off, const int* __restrict__ cnt, int s,
                       float* __restrict__ AGG, int isFirst,
                       unsigned short* __restrict__ Ghi, unsigned short* __restrict__ Glo,
                       int emit)
{
  int l = blockIdx.x, t = threadIdx.x;
  size_t b0 = (size_t)l*512 + t, b1 = b0 + 256;
  if (l >= 2000){
    AGG[b0] = 0.f; AGG[b1] = 0.f;
    if (emit){ Ghi[b0]=0; Glo[b0]=0; Ghi[b1]=0; Glo[b1]=0; }
    return;
  }
  int o = off[s*2000 + l], c = cnt[s*2000 + l];
  float a0 = isFirst ? 0.f : AGG[b0];
  float a1 = isFirst ? 0.f : AGG[b1];
  for (int i = 0; i < c; ++i){
    size_t p = (size_t)plist[o + i] * 512;
    a0 += bf2f(Hh[p + t])       + bf2f(Hl[p + t]);
    a1 += bf2f(Hh[p + 256 + t]) + bf2f(Hl[p + 256 + t]);
  }
  AGG[b0] = a0; AGG[b1] = a1;
  if (emit){
    unsigned short h0 = f2bf(a0); Ghi[b0]=h0; Glo[b0]=f2bf(a0 - bf2f(h0));
    unsigned short h1 = f2bf(a1); Ghi[b1]=h1; Glo[b1]=f2bf(a1 - bf2f(h1));
  }
}

// ---------------- VALU GEMM (readout only): C = relu?(A @ W^T + bias) ----------------
__global__ __launch_bounds__(256,2) void gemmv_k(
    const float* __restrict__ A, int lda, const float* __restrict__ W,
    const float* __restrict__ bias, float* __restrict__ C,
    int M, int N, int K, int relu)
{
  __shared__ float sA[64*32];
  __shared__ float sW[32*192];
  const int tid = threadIdx.x;
  const int colg = tid & 31, rowg = tid >> 5;
  const int m0 = blockIdx.x*64, n0 = blockIdx.y*192;
  float acc[8][6] = {};
  for (int k0 = 0; k0 < K; k0 += 32){
    __syncthreads();
#pragma unroll
    for (int u = 0; u < 2; ++u){
      int fi = tid + u*256; int row = fi >> 3, kqq = fi & 7;
      float4v v = *(const float4v*)(A + (size_t)(m0+row)*lda + k0 + kqq*4);
      *(float4v*)&sA[row*32 + kqq*4] = v;
    }
#pragma unroll
    for (int u = 0; u < 6; ++u){
      int fi = tid + u*256; int vc = fi >> 3, kqq = fi & 7;
      int wrow = n0 + vc;
      float4v v = {0.f,0.f,0.f,0.f};
      if (wrow < N) v = *(const float4v*)(W + (size_t)wrow*K + k0 + kqq*4);
      sW[(kqq*4+0)*192 + vc] = v.x;
      sW[(kqq*4+1)*192 + vc] = v.y;
      sW[(kqq*4+2)*192 + vc] = v.z;
      sW[(kqq*4+3)*192 + vc] = v.w;
    }
    __syncthreads();
#pragma unroll
    for (int kk = 0; kk < 32; ++kk){
      float a[8], w[6];
#pragma unroll
      for (int j = 0; j < 8; ++j) a[j] = sA[(rowg*8+j)*32 + kk];
#pragma unroll
      for (int i = 0; i < 6; ++i) w[i] = sW[kk*192 + colg*6 + i];
#pragma unroll
      for (int j = 0; j < 8; ++j)
#pragma unroll
        for (int i = 0; i < 6; ++i) acc[j][i] = fmaf(a[j], w[i], acc[j][i]);
    }
  }
#pragma unroll
  for (int j = 0; j < 8; ++j){
    int m = m0 + rowg*8 + j;
#pragma unroll
    for (int i = 0; i < 6; ++i){
      int col = n0 + colg*6 + i;
      if (col >= N) continue;
      float v = acc[j][i] + (bias ? bias[col] : 0.f);
      if (relu) v = fmaxf(v, 0.f);
      if (m >= M) v = 0.f;
      C[(size_t)m*N + col] = v;
    }
  }
}

// ---------------- final 128->1 dot per row ----------------
__global__ void dotf_k(const float* __restrict__ T2, const float* __restrict__ w3,
                       const float* __restrict__ b3, float* __restrict__ out, int M)
{
  int lane = threadIdx.x & 63, w = threadIdx.x >> 6;
  int m = blockIdx.x * 4 + w;
  if (m >= M) return;
  float s = T2[(size_t)m*128 + lane] * w3[lane]
          + T2[(size_t)m*128 + 64 + lane] * w3[64 + lane];
#pragma unroll
  for (int off = 32; off; off >>= 1) s += __shfl_xor(s, off);
  if (lane == 0) out[m] = s + b3[0];
}

extern "C" void kernel_launch(void* const* d_in, const int* in_sizes, int n_in,
                              void* d_out, int out_size, void* d_ws, size_t ws_size,
                              hipStream_t stream)
{
  const int*   links = (const int*)d_in[0];
  const int*   paths = (const int*)d_in[1];
  const int*   seqs  = (const int*)d_in[2];
  const float* cap   = (const float*)d_in[3];
  const float* bw    = (const float*)d_in[4];
  const float* Wih_p = (const float*)d_in[5];
  const float* Whh_p = (const float*)d_in[6];
  const float* bih_p = (const float*)d_in[7];
  const float* bhh_p = (const float*)d_in[8];
  const float* Wih_l = (const float*)d_in[9];
  const float* Whh_l = (const float*)d_in[10];
  const float* bih_l = (const float*)d_in[11];
  const float* bhh_l = (const float*)d_in[12];
  const float* d_w1 = (const float*)d_in[13]; const float* d_b1 = (const float*)d_in[14];
  const float* d_w2 = (const float*)d_in[15]; const float* d_b2 = (const float*)d_in[16];
  const float* d_w3 = (const float*)d_in[17]; const float* d_b3 = (const float*)d_in[18];
  const float* j_w1 = (const float*)d_in[19]; const float* j_b1 = (const float*)d_in[20];
  const float* j_w2 = (const float*)d_in[21]; const float* j_b2 = (const float*)d_in[22];
  const float* j_w3 = (const float*)d_in[23]; const float* j_b3 = (const float*)d_in[24];
  float* out = (float*)d_out;

  const int MpP = 20480;   // 640 m-blocks of 32 (80/XCD); padded & zeroed
  const int MpL = 2048;    // 64 m-blocks of 32 (8/XCD)
  char* p = (char*)d_ws;
  auto alloc = [&](size_t n){ char* r = p; p += (n + 255) & ~(size_t)255; return r; };
  float* P   = (float*)alloc((size_t)MpP*512*4);                 // final path state fp32 (readout)
  unsigned short* Phi[2]; unsigned short* Plo[2];
  Phi[0] = (unsigned short*)alloc((size_t)MpP*512*2);
  Plo[0] = (unsigned short*)alloc((size_t)MpP*512*2);
  Phi[1] = (unsigned short*)alloc((size_t)MpP*512*2);
  Plo[1] = (unsigned short*)alloc((size_t)MpP*512*2);
  unsigned short* Lhi[2]; unsigned short* Llo[2];
  Lhi[0] = (unsigned short*)alloc((size_t)MpL*512*2);
  Llo[0] = (unsigned short*)alloc((size_t)MpL*512*2);
  Lhi[1] = (unsigned short*)alloc((size_t)MpL*512*2);
  Llo[1] = (unsigned short*)alloc((size_t)MpL*512*2);
  float* LG  = (float*)alloc((size_t)MpL*1536*4);                // gi rows [2048,1536]
  float* AGG = (float*)alloc((size_t)MpL*512*4);
  unsigned short* AGh = (unsigned short*)alloc((size_t)MpL*512*2);
  unsigned short* AGl = (unsigned short*)alloc((size_t)MpL*512*2);
  unsigned short* WhhPh = (unsigned short*)alloc((size_t)1536*512*2);
  unsigned short* WhhPl = (unsigned short*)alloc((size_t)1536*512*2);
  unsigned short* WihPh = (unsigned short*)alloc((size_t)1536*512*2);
  unsigned short* WihPl = (unsigned short*)alloc((size_t)1536*512*2);
  unsigned short* WhhLh = (unsigned short*)alloc((size_t)1536*512*2);
  unsigned short* WhhLl = (unsigned short*)alloc((size_t)1536*512*2);
  unsigned short* WihLh = (unsigned short*)alloc((size_t)1536*512*2);
  unsigned short* WihLl = (unsigned short*)alloc((size_t)1536*512*2);
  int* cnt2  = (int*)alloc(12000*4);
  int* off2  = (int*)alloc(12000*4);
  int* cur2  = (int*)alloc(12000*4);
  int* plist = (int*)alloc(120000*4);
  int* plink = (int*)alloc(120000*4);
  // readout scratch aliases the (dead after the loop) hi/lo pair buffers
  float* t1 = (float*)Phi[0];   // needs 20032*256*4 = 19.6 MiB <= 20480*512*2 = 20.0 MiB
  float* t2 = (float*)Phi[1];   // needs 20032*128*4 =  9.8 MiB
  if ((size_t)(p - (char*)d_ws) > ws_size){
    sentf_k<<<(out_size+255)/256,256,0,stream>>>(out, out_size, 0.25f);
    return;
  }

  hipMemsetAsync(cnt2, 0, 12000*4, stream);
  prep_k<<<469,256,0,stream>>>(links, paths, seqs, plink, cnt2);
  scan_k<<<1,256,0,stream>>>(cnt2, off2, cur2);
  fill2_k<<<469,256,0,stream>>>(links, paths, seqs, cur2, plist);
  wcvt_k<<<3072,256,0,stream>>>(Whh_p, WhhPh, WhhPl, 1536*512);
  wcvt_k<<<3072,256,0,stream>>>(Wih_p, WihPh, WihPl, 1536*512);
  wcvt_k<<<3072,256,0,stream>>>(Whh_l, WhhLh, WhhLl, 1536*512);
  wcvt_k<<<3072,256,0,stream>>>(Wih_l, WihLh, WihLl, 1536*512);
  initp_k<<<(MpP*512)/256,256,0,stream>>>(bw,  Phi[0], Plo[0], Phi[1], Plo[1], 20000);
  initp_k<<<(MpL*512)/256,256,0,stream>>>(cap, Lhi[0], Llo[0], Lhi[1], Llo[1], 2000);

  int pb = 0, lb = 0;
  for (int t = 0; t < 8; ++t) {
    // LG = link_h @ Wih_p^T + bih_p  (gi rows for path entries)
    gmfma_k<<<64*8,128,0,stream>>>(Lhi[lb], Llo[lb], WihPh, WihPl, bih_p,
                                   (const float*)0, (const int*)0, 0,
                                   LG, (unsigned short*)0, (unsigned short*)0, 2000, 0, 0);
    for (int s6 = 0; s6 < 6; ++s6) {
      int last = (t==7 && s6==5) ? 1 : 0;
      gmfma_k<<<640*8,128,0,stream>>>(Phi[pb], Plo[pb], WhhPh, WhhPl, bhh_p,
                                      LG, plink, s6,
                                      P, Phi[pb^1], Plo[pb^1], 20000, 1, last);
      pb ^= 1;
      aggv_k<<<2048,256,0,stream>>>(Phi[pb], Plo[pb], plist, off2, cnt2, s6, AGG,
                                    (s6==0)?1:0, AGh, AGl, (s6==5)?1:0);
    }
    // GIL = agg @ Wih_l^T + bih_l (into LG); link_h = GRU(GIL, link_h)
    gmfma_k<<<64*8,128,0,stream>>>(AGh, AGl, WihLh, WihLl, bih_l,
                                   (const float*)0, (const int*)0, 0,
                                   LG, (unsigned short*)0, (unsigned short*)0, 2000, 0, 0);
    gmfma_k<<<64*8,128,0,stream>>>(Lhi[lb], Llo[lb], WhhLh, WhhLl, bhh_l,
                                   LG, (const int*)0, 0,
                                   (float*)0, Lhi[lb^1], Llo[lb^1], 2000, 1, 0);
    lb ^= 1;
  }

  // readout: delay
  gemmv_k<<<dim3(313,2),256,0,stream>>>(P, 512, d_w1, d_b1, t1, 20000, 256, 512, 1);
  gemmv_k<<<dim3(313,1),256,0,stream>>>(t1, 256, d_w2, d_b2, t2, 20000, 128, 256, 1);
  dotf_k<<<5000,256,0,stream>>>(t2, d_w3, d_b3, out, 20000);
  // readout: jitter
  gemmv_k<<<dim3(313,2),256,0,stream>>>(P, 512, j_w1, j_b1, t1, 20000, 256, 512, 1);
  gemmv_k<<<dim3(313,1),256,0,stream>>>(t1, 256, j_w2, j_b2, t2, 20000, 128, 256, 1);
  dotf_k<<<5000,256,0,stream>>>(t2, j_w3, j_b3, out + 20000, 20000);
}

// Round 7
// 8504.542 us; speedup vs baseline: 1.9344x; 1.9344x over previous
//
#include <hip/hip_runtime.h>
#include <stdint.h>

typedef __attribute__((ext_vector_type(4))) float float4v;
typedef __attribute__((ext_vector_type(8))) short short8v;   // 8 x bf16 (4 VGPRs)

static __device__ __forceinline__ float sigp(float x){ return 1.f/(1.f+expf(-x)); }

// fp32 -> bf16 (RNE) and back
static __device__ __forceinline__ unsigned short f2bf(float x){
  unsigned u = __float_as_uint(x);
  u += 0x7FFFu + ((u>>16)&1u);
  return (unsigned short)(u>>16);
}
static __device__ __forceinline__ float bf2f(unsigned short h){
  return __uint_as_float(((unsigned)h)<<16);
}

static __device__ __forceinline__ void gload16(const void* g, void* l){
  __builtin_amdgcn_global_load_lds((const __attribute__((address_space(1))) void*)g,
                                   (__attribute__((address_space(3))) void*)l, 16, 0, 0);
}

__global__ void sentf_k(float* __restrict__ o, int n, float v){
  int i = blockIdx.x*256 + threadIdx.x; if (i < n) o[i] = v;
}

// ---------------- prep: plink + histogram over (seq, link) ----------------
__global__ void prep_k(const int* __restrict__ links, const int* __restrict__ paths,
                       const int* __restrict__ seqs, int* __restrict__ plink,
                       int* __restrict__ cnt){
  int e = blockIdx.x*256 + threadIdx.x;
  if (e < 120000){
    int p = paths[e], s = seqs[e], l = links[e];
    plink[p*6 + s] = l;
    atomicAdd(&cnt[s*2000 + l], 1);
  }
}
__global__ void scan_k(const int* __restrict__ cnt, int* __restrict__ off, int* __restrict__ cur){
  __shared__ int part[256]; __shared__ int pref[256];
  int t = threadIdx.x;
  int lo = t*47, hi = lo+47; if (hi > 12000) hi = 12000;
  int s = 0;
  for (int i=lo;i<hi;i++) s += cnt[i];
  part[t] = s; __syncthreads();
  if (t==0){ int r=0; for (int i=0;i<256;i++){ pref[i]=r; r+=part[i]; } }
  __syncthreads();
  int r = pref[t];
  for (int i=lo;i<hi;i++){ off[i]=r; cur[i]=r; r+=cnt[i]; }
}
__global__ void fill2_k(const int* __restrict__ links, const int* __restrict__ paths,
                        const int* __restrict__ seqs, int* __restrict__ cur,
                        int* __restrict__ plist){
  int e = blockIdx.x*256 + threadIdx.x;
  if (e < 120000){
    int p = paths[e], s = seqs[e], l = links[e];
    int pos = atomicAdd(&cur[s*2000 + l], 1);
    plist[pos] = p;
  }
}

// ---------------- weight split: W -> (hi, lo) bf16 ----------------
__global__ void wcvt_k(const float* __restrict__ W, unsigned short* __restrict__ hi,
                       unsigned short* __restrict__ lo, int n){
  int i = blockIdx.x*256 + threadIdx.x;
  if (i < n){
    float x = W[i];
    unsigned short h = f2bf(x);
    hi[i] = h;
    lo[i] = f2bf(x - bf2f(h));
  }
}

// ---------------- state init: hi/lo pairs into both ping-pong buffers ----------------
__global__ void initp_k(const float* __restrict__ x0,
                        unsigned short* __restrict__ h0, unsigned short* __restrict__ l0,
                        unsigned short* __restrict__ h1, unsigned short* __restrict__ l1,
                        int Mreal){
  int i = blockIdx.x*256 + threadIdx.x;   // grid covers Mp*512
  int m = i >> 9, c = i & 511;
  float v = (c==0 && m < Mreal) ? x0[m] : 0.f;
  unsigned short hh = f2bf(v);
  unsigned short ll = f2bf(v - bf2f(hh));
  h0[i]=hh; l0[i]=ll; h1[i]=hh; l1[i]=ll;
}

// ---------------- MFMA split-bf16 GEMM, optionally fused GRU step ----------------
// C[M,1536] = A[M,512] @ W[1536,512]^T  via  Ahi@Whi + Alo@Whi + Ahi@Wlo
// tile: BM=128, BN=192 (3 gates x 64 cols), 4 waves, each 64x96 = 4x6 16x16x32 frags.
// XCD-aware flat grid (HW: XCD = bid % 8): X=bid&7, k=bid>>3, mblk=(k>>3)*8+X, cb=k&7.
// K-loop: 16 chunks of K=32; per chunk stage {Ahi,Alo,Whi,Wlo} once (10 gload_lds).
// Counted-vmcnt pipeline; per chunk:
//   vmcnt(10) -> barrier -> [ds_reads INTERLEAVED with MFMA by the compiler's own
//   partial lgkmcnt] -> lgkmcnt(0) -> barrier -> STAGE(kk+2, issue-only).
// The read->MFMA fence of the previous version is REMOVED: MFMA starts as soon as
// the first operand pair lands; barrier #2 (buffer-overwrite safety) sits after
// the MFMA cluster where reads are already drained.
// gru=0: OutF[m*1536 + gcol] = acc + bias[gcol]
// gru=1: fused gates; state hi/lo in (Ahi,Alo) -> (Ohi,Olo); fp32 out only if writeF.
__global__ __launch_bounds__(256,2) void gmfma_k(
    const unsigned short* __restrict__ Ahi, const unsigned short* __restrict__ Alo,
    const unsigned short* __restrict__ Whi, const unsigned short* __restrict__ Wlo,
    const float* __restrict__ bias, const float* __restrict__ GI,
    const int* __restrict__ plink, int s,
    float* __restrict__ OutF,
    unsigned short* __restrict__ Ohi, unsigned short* __restrict__ Olo,
    int M, int gru, int writeF)
{
  // buffer 0 / buffer 1 as distinct objects (alias analysis!)
  __shared__ unsigned short sAh0[128*32], sAl0[128*32];
  __shared__ unsigned short sBh0[192*32], sBl0[192*32];
  __shared__ unsigned short sAh1[128*32], sAl1[128*32];
  __shared__ unsigned short sBh1[192*32], sBl1[192*32];
  const int tid  = threadIdx.x;
  const int lane = tid & 63, wave = tid >> 6;
  const int wm = wave >> 1, wn = wave & 1;
  const int bid = blockIdx.x;
  const int X = bid & 7, kk2 = bid >> 3;
  const int m0 = ((kk2 >> 3)*8 + X) * 128;
  const int cb = kk2 & 7;
  const int c16 = lane & 15, kq = lane >> 4;

  // staging source offsets (bytes). LDS granule g holds global granule
  // (row = g>>2, kg = (g&3) ^ ((row>>1)&3)) -> swizzle via pre-swizzled SOURCE.
  int offA0, offA1;
  {
    int ga = tid;           int row = ga >> 2; int kg = (ga & 3) ^ ((row >> 1) & 3);
    offA0 = (m0 + row)*1024 + kg*16;
    ga = tid + 256;         row = ga >> 2;     kg = (ga & 3) ^ ((row >> 1) & 3);
    offA1 = (m0 + row)*1024 + kg*16;
  }
  int offB0, offB1, offB2;
  {
    int offs[3];
#pragma unroll
    for (int u = 0; u < 3; ++u){
      int gb = tid + u*256;
      int v  = gb >> 2;
      int kg = (gb & 3) ^ ((v >> 1) & 3);
      int wn_ = (v >= 96) ? 1 : 0;
      int uu  = v - wn_*96;
      int wr  = (uu >> 5)*512 + cb*64 + wn_*32 + (uu & 31);  // W row for tile col v
      offs[u] = wr*1024 + kg*16;
    }
    offB0 = offs[0]; offB1 = offs[1]; offB2 = offs[2];
  }
  // LDS dest granule offsets (wave-uniform), lane*16B added by HW
  const int gA0 = (wave*64      )*8, gA1 = (wave*64 + 256)*8;
  const int gB0 = (wave*64      )*8, gB1 = (wave*64 + 256)*8, gB2 = (wave*64 + 512)*8;

  // ds_read base offsets (shorts): swizzle bits invariant across mf/nf (16-row steps)
  const int rA = wm*64 + c16;
  const int rdA = (rA*4 + (kq ^ ((rA>>1)&3)))*8;
  const int vB = wn*96 + c16;
  const int rdB = (vB*4 + (kq ^ ((vB>>1)&3)))*8;

  float4v acc[4][6];
#pragma unroll
  for (int i = 0; i < 4; ++i)
#pragma unroll
    for (int j = 0; j < 6; ++j) acc[i][j] = (float4v){0.f,0.f,0.f,0.f};

  auto STAGE = [&](int kb, unsigned short* dAh, unsigned short* dAl,
                   unsigned short* dBh, unsigned short* dBl){
    const int kbb = kb*64;                 // 32 elems * 2B
    const char* ah = (const char*)Ahi + kbb;
    const char* al = (const char*)Alo + kbb;
    const char* wh = (const char*)Whi + kbb;
    const char* wl = (const char*)Wlo + kbb;
    gload16(ah + offA0, dAh + gA0);
    gload16(ah + offA1, dAh + gA1);
    gload16(al + offA0, dAl + gA0);
    gload16(al + offA1, dAl + gA1);
    gload16(wh + offB0, dBh + gB0);
    gload16(wh + offB1, dBh + gB1);
    gload16(wh + offB2, dBh + gB2);
    gload16(wl + offB0, dBl + gB0);
    gload16(wl + offB1, dBl + gB1);
    gload16(wl + offB2, dBl + gB2);
  };

  // one chunk: counted-vmcnt wait, barrier, reads+MFMA compiler-interleaved,
  // lgkm drain, barrier, stage-issue (no wait).
  auto CHUNK = [&](const unsigned short* tAh, const unsigned short* tAl,
                   const unsigned short* tBh, const unsigned short* tBl,
                   int stageKb, unsigned short* dAh, unsigned short* dAl,
                   unsigned short* dBh, unsigned short* dBl, int last){
    if (last) asm volatile("s_waitcnt vmcnt(0)");
    else      asm volatile("s_waitcnt vmcnt(10)");
    __builtin_amdgcn_s_barrier();
    __builtin_amdgcn_sched_barrier(0);     // reads must not hoist above barrier
    short8v ah[4], al[4], bh[6], bl[6];
#pragma unroll
    for (int mf = 0; mf < 4; ++mf) ah[mf] = *(const short8v*)(tAh + rdA + mf*512);
#pragma unroll
    for (int nf = 0; nf < 6; ++nf) bh[nf] = *(const short8v*)(tBh + rdB + nf*512);
#pragma unroll
    for (int mf = 0; mf < 4; ++mf) al[mf] = *(const short8v*)(tAl + rdA + mf*512);
#pragma unroll
    for (int nf = 0; nf < 6; ++nf) bl[nf] = *(const short8v*)(tBl + rdB + nf*512);
    // no fence here: compiler interleaves MFMA with the reads above using
    // its own partial lgkmcnt waits (m97-style near-optimal scheduling).
#pragma unroll
    for (int mf = 0; mf < 4; ++mf)
#pragma unroll
      for (int nf = 0; nf < 6; ++nf)
        acc[mf][nf] = __builtin_amdgcn_mfma_f32_16x16x32_bf16(ah[mf], bh[nf], acc[mf][nf], 0, 0, 0);
#pragma unroll
    for (int mf = 0; mf < 4; ++mf)
#pragma unroll
      for (int nf = 0; nf < 6; ++nf)
        acc[mf][nf] = __builtin_amdgcn_mfma_f32_16x16x32_bf16(al[mf], bh[nf], acc[mf][nf], 0, 0, 0);
#pragma unroll
    for (int mf = 0; mf < 4; ++mf)
#pragma unroll
      for (int nf = 0; nf < 6; ++nf)
        acc[mf][nf] = __builtin_amdgcn_mfma_f32_16x16x32_bf16(ah[mf], bl[nf], acc[mf][nf], 0, 0, 0);
    asm volatile("s_waitcnt lgkmcnt(0)");  // (already drained by MFMA consumption)
    __builtin_amdgcn_sched_barrier(0);
    __builtin_amdgcn_s_barrier();          // all waves done reading -> safe to overwrite
    if (stageKb >= 0) STAGE(stageKb, dAh, dAl, dBh, dBl);
  };

  STAGE(0, sAh0, sAl0, sBh0, sBl0);
  STAGE(1, sAh1, sAl1, sBh1, sBl1);
  for (int q = 0; q < 7; ++q){
    CHUNK(sAh0, sAl0, sBh0, sBl0, 2*q+2, sAh0, sAl0, sBh0, sBl0, 0);
    CHUNK(sAh1, sAl1, sBh1, sBl1, 2*q+3, sAh1, sAl1, sBh1, sBl1, 0);
  }
  CHUNK(sAh0, sAl0, sBh0, sBl0, -1, sAh0, sAl0, sBh0, sBl0, 0);   // chunk 14
  CHUNK(sAh1, sAl1, sBh1, sBl1, -1, sAh1, sAl1, sBh1, sBl1, 1);   // chunk 15 (drain)

  // epilogue. C/D frag: col = lane&15, row = (lane>>4)*4 + reg.
  if (!gru){
#pragma unroll
    for (int pp = 0; pp < 2; ++pp){
      const int col = cb*64 + wn*32 + pp*16 + c16;
      const float b0f = bias[col], b1f = bias[512+col], b2f = bias[1024+col];
#pragma unroll
      for (int mf = 0; mf < 4; ++mf){
        const int mb = m0 + wm*64 + mf*16 + kq*4;
#pragma unroll
        for (int r = 0; r < 4; ++r){
          const int m = mb + r;
          if (m < M){
            float* c = OutF + (size_t)m*1536 + col;
            c[0]    = acc[mf][0+pp][r] + b0f;
            c[512]  = acc[mf][2+pp][r] + b1f;
            c[1024] = acc[mf][4+pp][r] + b2f;
          }
        }
      }
    }
  } else {
#pragma unroll
    for (int pp = 0; pp < 2; ++pp){
      const int col = cb*64 + wn*32 + pp*16 + c16;
      const float br = bias[col], bz = bias[512+col], bn = bias[1024+col];
#pragma unroll
      for (int mf = 0; mf < 4; ++mf){
        const int mb = m0 + wm*64 + mf*16 + kq*4;
#pragma unroll
        for (int r = 0; r < 4; ++r){
          const int m = mb + r;
          if (m < M){
            const int gr = plink ? plink[m*6 + s] : m;
            const float* gi = GI + (size_t)gr*1536 + col;
            const size_t ix = (size_t)m*512 + col;
            float hold = bf2f(Ahi[ix]) + bf2f(Alo[ix]);
            float rr = sigp(gi[0]    + acc[mf][0+pp][r] + br);
            float zz = sigp(gi[512]  + acc[mf][2+pp][r] + bz);
            float nn = 2.f*sigp(2.f*(gi[1024] + rr*(acc[mf][4+pp][r] + bn))) - 1.f; // tanh
            float h  = (1.f - zz)*nn + zz*hold;
            unsigned short hh = f2bf(h);
            Ohi[ix] = hh;
            Olo[ix] = f2bf(h - bf2f(hh));
            if (writeF) OutF[ix] = h;
          }
        }
      }
    }
  }
}

// ---------------- per-step segment-sum over hi/lo state; emits hi/lo agg at s==5 ----------------
__global__ void aggv_k(const unsigned short* __restrict__ Hh, const unsigned short* __restrict__ Hl,
                       const int* __restrict__ plist,
                       const int* __restrict__ off, const int* __restrict__ cnt, int s,
                       float* __restrict__ AGG, int isFirst,
                       unsigned short* __restrict__ Ghi, unsigned short* __restrict__ Glo,
                       int emit)
{
  int l = blockIdx.x, t = threadIdx.x;
  size_t b0 = (size_t)l*512 + t, b1 = b0 + 256;
  if (l >= 2000){
    AGG[b0] = 0.f; AGG[b1] = 0.f;
    if (emit){ Ghi[b0]=0; Glo[b0]=0; Ghi[b1]=0; Glo[b1]=0; }
    return;
  }
  int o = off[s*2000 + l], c = cnt[s*2000 + l];
  float a0 = isFirst ? 0.f : AGG[b0];
  float a1 = isFirst ? 0.f : AGG[b1];
  for (int i = 0; i < c; ++i){
    size_t p = (size_t)plist[o + i] * 512;
    a0 += bf2f(Hh[p + t])       + bf2f(Hl[p + t]);
    a1 += bf2f(Hh[p + 256 + t]) + bf2f(Hl[p + 256 + t]);
  }
  AGG[b0] = a0; AGG[b1] = a1;
  if (emit){
    unsigned short h0 = f2bf(a0); Ghi[b0]=h0; Glo[b0]=f2bf(a0 - bf2f(h0));
    unsigned short h1 = f2bf(a1); Ghi[b1]=h1; Glo[b1]=f2bf(a1 - bf2f(h1));
  }
}

// ---------------- VALU GEMM (readout only): C = relu?(A @ W^T + bias) ----------------
__global__ __launch_bounds__(256,2) void gemmv_k(
    const float* __restrict__ A, int lda, const float* __restrict__ W,
    const float* __restrict__ bias, float* __restrict__ C,
    int M, int N, int K, int relu)
{
  __shared__ float sA[64*32];
  __shared__ float sW[32*192];
  const int tid = threadIdx.x;
  const int colg = tid & 31, rowg = tid >> 5;
  const int m0 = blockIdx.x*64, n0 = blockIdx.y*192;
  float acc[8][6] = {};
  for (int k0 = 0; k0 < K; k0 += 32){
    __syncthreads();
#pragma unroll
    for (int u = 0; u < 2; ++u){
      int fi = tid + u*256; int row = fi >> 3, kqq = fi & 7;
      float4v v = *(const float4v*)(A + (size_t)(m0+row)*lda + k0 + kqq*4);
      *(float4v*)&sA[row*32 + kqq*4] = v;
    }
#pragma unroll
    for (int u = 0; u < 6; ++u){
      int fi = tid + u*256; int vc = fi >> 3, kqq = fi & 7;
      int wrow = n0 + vc;
      float4v v = {0.f,0.f,0.f,0.f};
      if (wrow < N) v = *(const float4v*)(W + (size_t)wrow*K + k0 + kqq*4);
      sW[(kqq*4+0)*192 + vc] = v.x;
      sW[(kqq*4+1)*192 + vc] = v.y;
      sW[(kqq*4+2)*192 + vc] = v.z;
      sW[(kqq*4+3)*192 + vc] = v.w;
    }
    __syncthreads();
#pragma unroll
    for (int kk = 0; kk < 32; ++kk){
      float a[8], w[6];
#pragma unroll
      for (int j = 0; j < 8; ++j) a[j] = sA[(rowg*8+j)*32 + kk];
#pragma unroll
      for (int i = 0; i < 6; ++i) w[i] = sW[kk*192 + colg*6 + i];
#pragma unroll
      for (int j = 0; j < 8; ++j)
#pragma unroll
        for (int i = 0; i < 6; ++i) acc[j][i] = fmaf(a[j], w[i], acc[j][i]);
    }
  }
#pragma unroll
  for (int j = 0; j < 8; ++j){
    int m = m0 + rowg*8 + j;
#pragma unroll
    for (int i = 0; i < 6; ++i){
      int col = n0 + colg*6 + i;
      if (col >= N) continue;
      float v = acc[j][i] + (bias ? bias[col] : 0.f);
      if (relu) v = fmaxf(v, 0.f);
      if (m >= M) v = 0.f;
      C[(size_t)m*N + col] = v;
    }
  }
}

// ---------------- final 128->1 dot per row ----------------
__global__ void dotf_k(const float* __restrict__ T2, const float* __restrict__ w3,
                       const float* __restrict__ b3, float* __restrict__ out, int M)
{
  int lane = threadIdx.x & 63, w = threadIdx.x >> 6;
  int m = blockIdx.x * 4 + w;
  if (m >= M) return;
  float s = T2[(size_t)m*128 + lane] * w3[lane]
          + T2[(size_t)m*128 + 64 + lane] * w3[64 + lane];
#pragma unroll
  for (int off = 32; off; off >>= 1) s += __shfl_xor(s, off);
  if (lane == 0) out[m] = s + b3[0];
}

extern "C" void kernel_launch(void* const* d_in, const int* in_sizes, int n_in,
                              void* d_out, int out_size, void* d_ws, size_t ws_size,
                              hipStream_t stream)
{
  const int*   links = (const int*)d_in[0];
  const int*   paths = (const int*)d_in[1];
  const int*   seqs  = (const int*)d_in[2];
  const float* cap   = (const float*)d_in[3];
  const float* bw    = (const float*)d_in[4];
  const float* Wih_p = (const float*)d_in[5];
  const float* Whh_p = (const float*)d_in[6];
  const float* bih_p = (const float*)d_in[7];
  const float* bhh_p = (const float*)d_in[8];
  const float* Wih_l = (const float*)d_in[9];
  const float* Whh_l = (const float*)d_in[10];
  const float* bih_l = (const float*)d_in[11];
  const float* bhh_l = (const float*)d_in[12];
  const float* d_w1 = (const float*)d_in[13]; const float* d_b1 = (const float*)d_in[14];
  const float* d_w2 = (const float*)d_in[15]; const float* d_b2 = (const float*)d_in[16];
  const float* d_w3 = (const float*)d_in[17]; const float* d_b3 = (const float*)d_in[18];
  const float* j_w1 = (const float*)d_in[19]; const float* j_b1 = (const float*)d_in[20];
  const float* j_w2 = (const float*)d_in[21]; const float* j_b2 = (const float*)d_in[22];
  const float* j_w3 = (const float*)d_in[23]; const float* j_b3 = (const float*)d_in[24];
  float* out = (float*)d_out;

  const int MpP = 20480;   // 160 * 128 (padded so XCD mapping is total: 20 m-blocks/XCD)
  const int MpL = 2048;    // 16 * 128
  char* p = (char*)d_ws;
  auto alloc = [&](size_t n){ char* r = p; p += (n + 255) & ~(size_t)255; return r; };
  float* P   = (float*)alloc((size_t)MpP*512*4);                 // final path state fp32 (readout)
  unsigned short* Phi[2]; unsigned short* Plo[2];
  Phi[0] = (unsigned short*)alloc((size_t)MpP*512*2);
  Plo[0] = (unsigned short*)alloc((size_t)MpP*512*2);
  Phi[1] = (unsigned short*)alloc((size_t)MpP*512*2);
  Plo[1] = (unsigned short*)alloc((size_t)MpP*512*2);
  unsigned short* Lhi[2]; unsigned short* Llo[2];
  Lhi[0] = (unsigned short*)alloc((size_t)MpL*512*2);
  Llo[0] = (unsigned short*)alloc((size_t)MpL*512*2);
  Lhi[1] = (unsigned short*)alloc((size_t)MpL*512*2);
  Llo[1] = (unsigned short*)alloc((size_t)MpL*512*2);
  float* LG  = (float*)alloc((size_t)MpL*1536*4);                // gi rows [2048,1536]
  float* AGG = (float*)alloc((size_t)MpL*512*4);
  unsigned short* AGh = (unsigned short*)alloc((size_t)MpL*512*2);
  unsigned short* AGl = (unsigned short*)alloc((size_t)MpL*512*2);
  unsigned short* WhhPh = (unsigned short*)alloc((size_t)1536*512*2);
  unsigned short* WhhPl = (unsigned short*)alloc((size_t)1536*512*2);
  unsigned short* WihPh = (unsigned short*)alloc((size_t)1536*512*2);
  unsigned short* WihPl = (unsigned short*)alloc((size_t)1536*512*2);
  unsigned short* WhhLh = (unsigned short*)alloc((size_t)1536*512*2);
  unsigned short* WhhLl = (unsigned short*)alloc((size_t)1536*512*2);
  unsigned short* WihLh = (unsigned short*)alloc((size_t)1536*512*2);
  unsigned short* WihLl = (unsigned short*)alloc((size_t)1536*512*2);
  int* cnt2  = (int*)alloc(12000*4);
  int* off2  = (int*)alloc(12000*4);
  int* cur2  = (int*)alloc(12000*4);
  int* plist = (int*)alloc(120000*4);
  int* plink = (int*)alloc(120000*4);
  // readout scratch aliases the (dead after the loop) hi/lo pair buffers
  float* t1 = (float*)Phi[0];   // needs 20032*256*4 = 19.6 MiB <= 20480*512*2 = 20.0 MiB
  float* t2 = (float*)Phi[1];   // needs 20032*128*4 =  9.8 MiB
  if ((size_t)(p - (char*)d_ws) > ws_size){
    sentf_k<<<(out_size+255)/256,256,0,stream>>>(out, out_size, 0.25f);
    return;
  }

  hipMemsetAsync(cnt2, 0, 12000*4, stream);
  prep_k<<<469,256,0,stream>>>(links, paths, seqs, plink, cnt2);
  scan_k<<<1,256,0,stream>>>(cnt2, off2, cur2);
  fill2_k<<<469,256,0,stream>>>(links, paths, seqs, cur2, plist);
  wcvt_k<<<3072,256,0,stream>>>(Whh_p, WhhPh, WhhPl, 1536*512);
  wcvt_k<<<3072,256,0,stream>>>(Wih_p, WihPh, WihPl, 1536*512);
  wcvt_k<<<3072,256,0,stream>>>(Whh_l, WhhLh, WhhLl, 1536*512);
  wcvt_k<<<3072,256,0,stream>>>(Wih_l, WihLh, WihLl, 1536*512);
  initp_k<<<(MpP*512)/256,256,0,stream>>>(bw,  Phi[0], Plo[0], Phi[1], Plo[1], 20000);
  initp_k<<<(MpL*512)/256,256,0,stream>>>(cap, Lhi[0], Llo[0], Lhi[1], Llo[1], 2000);

  int pb = 0, lb = 0;
  for (int t = 0; t < 8; ++t) {
    // LG = link_h @ Wih_p^T + bih_p  (gi rows for path entries)
    gmfma_k<<<16*8,256,0,stream>>>(Lhi[lb], Llo[lb], WihPh, WihPl, bih_p,
                                   (const float*)0, (const int*)0, 0,
                                   LG, (unsigned short*)0, (unsigned short*)0, 2000, 0, 0);
    for (int s6 = 0; s6 < 6; ++s6) {
      int last = (t==7 && s6==5) ? 1 : 0;
      gmfma_k<<<160*8,256,0,stream>>>(Phi[pb], Plo[pb], WhhPh, WhhPl, bhh_p,
                                      LG, plink, s6,
                                      P, Phi[pb^1], Plo[pb^1], 20000, 1, last);
      pb ^= 1;
      aggv_k<<<2048,256,0,stream>>>(Phi[pb], Plo[pb], plist, off2, cnt2, s6, AGG,
                                    (s6==0)?1:0, AGh, AGl, (s6==5)?1:0);
    }
    // GIL = agg @ Wih_l^T + bih_l (into LG); link_h = GRU(GIL, link_h)
    gmfma_k<<<16*8,256,0,stream>>>(AGh, AGl, WihLh, WihLl, bih_l,
                                   (const float*)0, (const int*)0, 0,
                                   LG, (unsigned short*)0, (unsigned short*)0, 2000, 0, 0);
    gmfma_k<<<16*8,256,0,stream>>>(Lhi[lb], Llo[lb], WhhLh, WhhLl, bhh_l,
                                   LG, (const int*)0, 0,
                                   (float*)0, Lhi[lb^1], Llo[lb^1], 2000, 1, 0);
    lb ^= 1;
  }

  // readout: delay
  gemmv_k<<<dim3(313,2),256,0,stream>>>(P, 512, d_w1, d_b1, t1, 20000, 256, 512, 1);
  gemmv_k<<<dim3(313,1),256,0,stream>>>(t1, 256, d_w2, d_b2, t2, 20000, 128, 256, 1);
  dotf_k<<<5000,256,0,stream>>>(t2, d_w3, d_b3, out, 20000);
  // readout: jitter
  gemmv_k<<<dim3(313,2),256,0,stream>>>(P, 512, j_w1, j_b1, t1, 20000, 256, 512, 1);
  gemmv_k<<<dim3(313,1),256,0,stream>>>(t1, 256, j_w2, j_b2, t2, 20000, 128, 256, 1);
  dotf_k<<<5000,256,0,stream>>>(t2, j_w3, j_b3, out + 20000, 20000);
}